// Round 9
// baseline (225.506 us; speedup 1.0000x reference)
//
#include <hip/hip_runtime.h>
#include <hip/hip_bf16.h>
#include <cstdint>
#include <cstddef>

// R9: (1) REVERT attention to R7's split-2/two-barrier/896-block kernel —
// R8's explicit pipeline halved the grid and LOST the implicit wave-overlap
// (occ 26->17%, 62->74us): the guide's pitfall #5 measured live. Keep exp2.
// (2) gemm2 was 74us at 131 TF: grid 384 = 1.5 blocks/CU starvation. New
// gemm64 (64x128 tile): 768 blocks, LDS 24KB -> 6 blocks/CU.
// gemm1 (128x128), cvt3, ln_inplace unchanged.

typedef __attribute__((ext_vector_type(8))) short short8;
typedef __attribute__((ext_vector_type(4))) short short4_;
typedef __attribute__((ext_vector_type(4))) float float4_;

#if __has_builtin(__builtin_amdgcn_exp2f)
#define EXP2(x) __builtin_amdgcn_exp2f(x)
#else
#define EXP2(x) exp2f(x)
#endif

__device__ __forceinline__ float bf2f(short s) {
    unsigned int u = ((unsigned int)(unsigned short)s) << 16;
    float f;
    __builtin_memcpy(&f, &u, 4);
    return f;
}
__device__ __forceinline__ short f2bf(float f) {
    unsigned int u;
    __builtin_memcpy(&u, &f, 4);
    u += 0x7fffu + ((u >> 16) & 1u);   // round-to-nearest-even
    return (short)(u >> 16);
}
__device__ __forceinline__ short f2bf_trunc(float f) {
    unsigned int u;
    __builtin_memcpy(&u, &f, 4);
    return (short)(u >> 16);
}
__device__ __forceinline__ short8 f8_to_bf8(const float* __restrict__ p) {
    float4_ a = *(const float4_*)(p);
    float4_ b = *(const float4_*)(p + 4);
    short8 r;
    r[0] = f2bf(a[0]); r[1] = f2bf(a[1]); r[2] = f2bf(a[2]); r[3] = f2bf(a[3]);
    r[4] = f2bf(b[0]); r[5] = f2bf(b[1]); r[6] = f2bf(b[2]); r[7] = f2bf(b[3]);
    return r;
}
__device__ __forceinline__ void gll16(const short* g, short* l) {
    __builtin_amdgcn_global_load_lds(
        (const __attribute__((address_space(1))) unsigned int*)g,
        (__attribute__((address_space(3))) unsigned int*)l, 16, 0, 0);
}

#define LDT 72

// ---- cvt3: fp32->bf16 for x / w_qkv / w_out -------------------------------
__global__ __launch_bounds__(256) void cvt3(
    const float* __restrict__ a, int na, const float* __restrict__ b, int nb,
    const float* __restrict__ c, int nc,
    short* __restrict__ oa, short* __restrict__ ob, short* __restrict__ oc)
{
    int i = (blockIdx.x * 256 + threadIdx.x) * 8;
    if (i < na) {
        *(short8*)&oa[i] = f8_to_bf8(a + i);
    } else if (i < na + nb) {
        int j = i - na;
        *(short8*)&ob[j] = f8_to_bf8(b + j);
    } else {
        int j = i - na - nb;
        if (j < nc) *(short8*)&oc[j] = f8_to_bf8(c + j);
    }
}

// ---- gemm128: qkv[8192,2304](bf16) = xb @ wqkvb^T + b_qkv, q-mask --------
__global__ __launch_bounds__(256) void gemm128(
    const short* __restrict__ A, int lda,
    const short* __restrict__ B,
    const float* __restrict__ bias,
    short* __restrict__ C,
    int N, int K)
{
    __shared__ short As[128 * 64];   // chunk-swizzled: slot(r,c)=G(r, c^(r&7))
    __shared__ short Bs[128 * 64];
    const int tid  = threadIdx.x;
    const int wave = tid >> 6, lane = tid & 63;
    const int quad = lane >> 4, l16 = lane & 15;
    const int wr = wave >> 1, wc = wave & 1;
    const int m0 = blockIdx.y * 128, n0 = blockIdx.x * 128;
    const int lrow   = lane >> 3;
    const int lchunk = (lane & 7) ^ lrow;

    const short* Abase = A + (size_t)(m0 + wave * 32 + lrow) * lda + lchunk * 8;
    const short* Bbase = B + (size_t)(n0 + wave * 32 + lrow) * (size_t)K + lchunk * 8;
    short* AsW = &As[(wave * 32) * 64];
    short* BsW = &Bs[(wave * 32) * 64];

    float4_ acc[4][4] = {};

    for (int k0 = 0; k0 < K; k0 += 64) {
        __syncthreads();
        #pragma unroll
        for (int i = 0; i < 4; i++) {
            gll16(Abase + (size_t)(i * 8) * lda + k0, AsW + (i * 8) * 64);
            gll16(Bbase + (size_t)(i * 8) * K   + k0, BsW + (i * 8) * 64);
        }
        __syncthreads();
        #pragma unroll
        for (int ks = 0; ks < 2; ks++) {
            short8 af[4], bf[4];
            const int ca = ((ks * 4 + quad) ^ (l16 & 7)) * 8;
            #pragma unroll
            for (int t = 0; t < 4; t++) {
                af[t] = *(const short8*)&As[(wr * 64 + t * 16 + l16) * 64 + ca];
                bf[t] = *(const short8*)&Bs[(wc * 64 + t * 16 + l16) * 64 + ca];
            }
            #pragma unroll
            for (int mt = 0; mt < 4; mt++)
                #pragma unroll
                for (int nt = 0; nt < 4; nt++)
                    acc[mt][nt] = __builtin_amdgcn_mfma_f32_16x16x32_bf16(
                        af[mt], bf[nt], acc[mt][nt], 0, 0, 0);
        }
    }

    #pragma unroll
    for (int nt = 0; nt < 4; nt++) {
        const int col = n0 + wc * 64 + nt * 16 + l16;
        const float bv = bias[col];
        const int g = col >> 8;
        #pragma unroll
        for (int mt = 0; mt < 4; mt++) {
            #pragma unroll
            for (int r = 0; r < 4; r++) {
                int row = m0 + wr * 64 + mt * 16 + quad * 4 + r;
                bool cov = (col >= 768) || (g == 0) ||
                           (g == 1 && (row & 1) == 1) ||
                           (g == 2 && (row & 3) == 2);
                C[(size_t)row * N + col] = cov ? f2bf(acc[mt][nt][r] + bv) : (short)0;
            }
        }
    }
}

// ---- gemm64: out[8192,768](fp32) = A[M,K](lda) @ B[N,K]^T + bias ---------
// 64x128 tile: grid (768/128)x(8192/64)=768 blocks (vs 384 at 128x128 = the
// R8 starvation). LDS 24KB -> 6 blocks/CU. Wave w: 32 rows x 64 cols.
__global__ __launch_bounds__(256) void gemm64(
    const short* __restrict__ A, int lda,
    const short* __restrict__ B,
    const float* __restrict__ bias,
    float* __restrict__ C,
    int N, int K)
{
    __shared__ short As[64 * 64];    // 8KB
    __shared__ short Bs[128 * 64];   // 16KB
    const int tid  = threadIdx.x;
    const int wave = tid >> 6, lane = tid & 63;
    const int quad = lane >> 4, l16 = lane & 15;
    const int wr = wave >> 1, wc = wave & 1;
    const int m0 = blockIdx.y * 64, n0 = blockIdx.x * 128;
    const int lrow   = lane >> 3;
    const int lchunk = (lane & 7) ^ lrow;

    // wave w stages A rows {w*8+lrow, +32}, B rows {w*8+lrow + r*32, r=0..3}
    const short* Abase = A + (size_t)(m0 + wave * 8 + lrow) * lda + lchunk * 8;
    const short* Bbase = B + (size_t)(n0 + wave * 8 + lrow) * (size_t)K + lchunk * 8;
    short* AsW = &As[(wave * 8) * 64];
    short* BsW = &Bs[(wave * 8) * 64];

    float4_ acc[2][4] = {};

    for (int k0 = 0; k0 < K; k0 += 64) {
        __syncthreads();
        gll16(Abase + k0, AsW);
        gll16(Abase + (size_t)32 * lda + k0, AsW + 32 * 64);
        #pragma unroll
        for (int i = 0; i < 4; i++)
            gll16(Bbase + (size_t)(i * 32) * K + k0, BsW + (i * 32) * 64);
        __syncthreads();
        #pragma unroll
        for (int ks = 0; ks < 2; ks++) {
            short8 af[2], bf[4];
            const int ca = ((ks * 4 + quad) ^ (l16 & 7)) * 8;
            #pragma unroll
            for (int t = 0; t < 2; t++)
                af[t] = *(const short8*)&As[(wr * 32 + t * 16 + l16) * 64 + ca];
            #pragma unroll
            for (int t = 0; t < 4; t++)
                bf[t] = *(const short8*)&Bs[(wc * 64 + t * 16 + l16) * 64 + ca];
            #pragma unroll
            for (int mt = 0; mt < 2; mt++)
                #pragma unroll
                for (int nt = 0; nt < 4; nt++)
                    acc[mt][nt] = __builtin_amdgcn_mfma_f32_16x16x32_bf16(
                        af[mt], bf[nt], acc[mt][nt], 0, 0, 0);
        }
    }

    #pragma unroll
    for (int nt = 0; nt < 4; nt++) {
        const int col = n0 + wc * 64 + nt * 16 + l16;
        const float bv = bias[col];
        #pragma unroll
        for (int mt = 0; mt < 2; mt++)
            #pragma unroll
            for (int r = 0; r < 4; r++) {
                int row = m0 + wr * 32 + mt * 16 + quad * 4 + r;
                C[(size_t)row * N + col] = acc[mt][nt][r] + bv;
            }
    }
}

// ---- Split-K dilated attention (R7 structure), Q-tile 128 -----------------
// Grid: 28 sh * 16 qt * 2 halves = 896. Two barriers/iter; TLP does the
// latency hiding (R8's explicit pipeline measured WORSE: 62->74us).
__global__ __launch_bounds__(256, 4) void dilated_attn_split(
    const short* __restrict__ qkv, short* __restrict__ Obuf,
    float* __restrict__ lbuf)
{
    __shared__ short Ks[64 * 64];       // unpadded; chunk-XOR swizzled (DMA)
    __shared__ short Vt[64 * LDT];      // Vt[d][key], key cols XOR-swizzled
    __shared__ short Ps[4 * 32 * LDT];  // per-wave 32-row P, column-swizzled

    const int bx = blockIdx.x;
    const int h  = bx & 1;
    const int qt = (bx >> 1) & 15;
    const int sh = bx >> 5;   // 0..27

    int g, seg, s, rate, off0;
    if (sh < 16)      { g = 0; seg = sh >> 2;        s = 2048; rate = 1; off0 = 0; }
    else if (sh < 24) { g = 1; seg = (sh - 16) >> 2; s = 4096; rate = 2; off0 = 1; }
    else              { g = 2; seg = 0;              s = 8192; rate = 4; off0 = 2; }
    const int head = g * 4 + (sh & 3);

    const int tid  = threadIdx.x;
    const int wave = tid >> 6, lane = tid & 63, quad = lane >> 4, l16 = lane & 15;
    const int srow = tid >> 2, scol = (tid & 3) * 16;   // V-staging map

    // ---- Q frags direct global->regs, pre-scaled by 0.125*log2(e) --------
    short8 aq[2][2];
    #pragma unroll
    for (int rg = 0; rg < 2; rg++) {
        int t = qt * 128 + wave * 32 + rg * 16 + l16;
        size_t pos = (size_t)seg * s + off0 + (size_t)t * rate;
        const short* qsrc = qkv + pos * 2304 + head * 64 + quad * 8;
        #pragma unroll
        for (int ks = 0; ks < 2; ks++) {
            short8 q = *(const short8*)(qsrc + ks * 32);
            #pragma unroll
            for (int e = 0; e < 8; e++) q[e] = f2bf(bf2f(q[e]) * 0.1803368801111244f);
            aq[rg][ks] = q;
        }
    }

    const int krow0  = wave * 8 + (lane >> 3);
    const int kchunk = (lane & 7) ^ (lane >> 3);
    const size_t kstep = (size_t)64 * rate * 2304;
    int k0 = h * 16 * 64;
    const short* kg0 = qkv + ((size_t)seg * s + off0 + (size_t)(k0 + krow0) * rate) * 2304
                           + 768 + head * 64 + kchunk * 8;
    const short* kg1 = kg0 + (size_t)32 * rate * 2304;
    short* kd0 = &Ks[(wave * 8) * 64];
    short* kd1 = kd0 + 32 * 64;
    const short* vg = qkv + ((size_t)seg * s + off0 + (size_t)(k0 + srow) * rate) * 2304
                          + 1536 + head * 64 + scol;

    float lrow[2][4] = {};
    float4_ oacc[2][4] = {};
    short* pw = &Ps[wave * 32 * LDT];
    const int cswap = (lane >> 5) & 1;
    const int pswz  = (l16 & 8) << 1;
    const int vswz  = scol;

    for (int j = 0; j < 16; j++) {
        __syncthreads();   // prev iter's frag reads done
        gll16(kg0, kd0);
        gll16(kg1, kd1);
        {   // V transposed scatter (swizzled key columns)
            short8 v0 = *(const short8*)(vg);
            short8 v1 = *(const short8*)(vg + 8);
            #pragma unroll
            for (int e = 0; e < 8; e++) Vt[(scol + e) * LDT + (srow ^ vswz)] = v0[e];
            #pragma unroll
            for (int e = 0; e < 8; e++) Vt[(scol + 8 + e) * LDT + (srow ^ vswz)] = v1[e];
        }
        kg0 += kstep; kg1 += kstep; vg += kstep;
        __syncthreads();   // K DMA + V scatter visible

        // S' = (Q*c) K^T : 32 q-rows x 64 keys per wave
        float4_ sacc[2][4] = {};
        #pragma unroll
        for (int ks = 0; ks < 2; ks++) {
            #pragma unroll
            for (int kt = 0; kt < 4; kt++) {
                short8 bk = *(const short8*)&Ks[(kt * 16 + l16) * 64
                                                + (((quad + 4 * ks) ^ (l16 & 7)) * 8)];
                #pragma unroll
                for (int rg = 0; rg < 2; rg++)
                    sacc[rg][kt] = __builtin_amdgcn_mfma_f32_16x16x32_bf16(
                        aq[rg][ks], bk, sacc[rg][kt], 0, 0, 0);
            }
        }

        // P = exp2(S'), per-lane partial sums, stash to LDS
        #pragma unroll
        for (int rg = 0; rg < 2; rg++) {
            #pragma unroll
            for (int r = 0; r < 4; r++) {
                float p0 = EXP2(sacc[rg][0][r]), p1 = EXP2(sacc[rg][1][r]);
                float p2 = EXP2(sacc[rg][2][r]), p3 = EXP2(sacc[rg][3][r]);
                short* prow = &pw[(rg * 16 + quad * 4 + r) * LDT + l16];
                prow[(0 ^ cswap) * 16] = f2bf_trunc(p0);
                prow[(1 ^ cswap) * 16] = f2bf_trunc(p1);
                prow[(2 ^ cswap) * 16] = f2bf_trunc(p2);
                prow[(3 ^ cswap) * 16] = f2bf_trunc(p3);
                lrow[rg][r] += (p0 + p1) + (p2 + p3);
            }
        }

        // O += P @ V
        #pragma unroll
        for (int ks = 0; ks < 2; ks++) {
            short8 ap[2];
            #pragma unroll
            for (int rg = 0; rg < 2; rg++)
                ap[rg] = *(const short8*)&pw[(rg * 16 + l16) * LDT
                                             + ((ks * 32 + quad * 8) ^ pswz)];
            #pragma unroll
            for (int nt = 0; nt < 4; nt++) {
                short8 bv = *(const short8*)&Vt[(nt * 16 + l16) * LDT
                                                + ((ks * 32 + quad * 8) ^ (nt * 16))];
                #pragma unroll
                for (int rg = 0; rg < 2; rg++)
                    oacc[rg][nt] = __builtin_amdgcn_mfma_f32_16x16x32_bf16(
                        ap[rg], bv, oacc[rg][nt], 0, 0, 0);
            }
        }
    }

    // row-sum reduction across the quad's 16 lanes; write partials
    #pragma unroll
    for (int rg = 0; rg < 2; rg++) {
        #pragma unroll
        for (int r = 0; r < 4; r++) {
            float v = lrow[rg][r];
            #pragma unroll
            for (int off = 1; off < 16; off <<= 1) v += __shfl_xor(v, off, 64);
            int qrow = wave * 32 + rg * 16 + quad * 4 + r;
            short* od = Obuf + ((size_t)bx * 128 + qrow) * 64;
            #pragma unroll
            for (int nt = 0; nt < 4; nt++)
                od[nt * 16 + l16] = f2bf(oacc[rg][nt][r]);
            if (l16 == 0) lbuf[(size_t)bx * 128 + qrow] = v;
        }
    }
}

// ---- combine: O = (O0+O1)/(l0+l1), scatter into q section -----------------
__global__ __launch_bounds__(256) void attn_combine(
    const short* __restrict__ Obuf, const float* __restrict__ lbuf,
    short* __restrict__ qkv)
{
    const int p  = blockIdx.x;
    const int qt = p & 15;
    const int sh = p >> 4;

    int g, seg, s, rate, off0;
    if (sh < 16)      { g = 0; seg = sh >> 2;        s = 2048; rate = 1; off0 = 0; }
    else if (sh < 24) { g = 1; seg = (sh - 16) >> 2; s = 4096; rate = 2; off0 = 1; }
    else              { g = 2; seg = 0;              s = 8192; rate = 4; off0 = 2; }
    const int head = g * 4 + (sh & 3);

    const int tid = threadIdx.x;
    const int row = tid >> 1, dbase = (tid & 1) * 32;

    const short* o0 = Obuf + ((size_t)(p * 2) * 128 + row) * 64 + dbase;
    const short* o1 = o0 + 128 * 64;
    const float  li = 1.0f / (lbuf[(size_t)(p * 2) * 128 + row] +
                              lbuf[(size_t)(p * 2 + 1) * 128 + row]);

    int t = qt * 128 + row;
    size_t pos = (size_t)seg * s + off0 + (size_t)t * rate;
    short* dst = qkv + pos * 2304 + head * 64 + dbase;

    #pragma unroll
    for (int c = 0; c < 4; c++) {
        short8 a = *(const short8*)(o0 + c * 8);
        short8 b = *(const short8*)(o1 + c * 8);
        short8 r;
        #pragma unroll
        for (int e = 0; e < 8; e++) r[e] = f2bf((bf2f(a[e]) + bf2f(b[e])) * li);
        *(short8*)(dst + c * 8) = r;
    }
}

// ---- Fused LayerNorm (stats + apply), in-place on q section ---------------
__global__ __launch_bounds__(256) void ln_inplace(
    short* __restrict__ qkv, const float* __restrict__ gamma,
    const float* __restrict__ beta)
{
    const int row  = blockIdx.x * 4 + (threadIdx.x >> 6);
    const int lane = threadIdx.x & 63;
    short* src = qkv + (size_t)row * 2304;

    short8  a = *(const short8*)&src[lane * 8];
    short4_ b = *(const short4_*)&src[512 + lane * 4];
    float v[12];
    #pragma unroll
    for (int e = 0; e < 8; e++) v[e] = bf2f(a[e]);
    #pragma unroll
    for (int e = 0; e < 4; e++) v[8 + e] = bf2f(b[e]);

    float sum = 0.f, sq = 0.f;
    #pragma unroll
    for (int e = 0; e < 12; e++) { sum += v[e]; sq += v[e] * v[e]; }
    #pragma unroll
    for (int off = 1; off < 64; off <<= 1) {
        sum += __shfl_xor(sum, off, 64);
        sq  += __shfl_xor(sq,  off, 64);
    }
    float mean = sum * (1.0f / 768.0f);
    float var  = sq * (1.0f / 768.0f) - mean * mean;
    float rstd = rsqrtf(var + 1e-5f);

    short8 o8; short4_ o4;
    #pragma unroll
    for (int e = 0; e < 8; e++)
        o8[e] = f2bf((v[e] - mean) * rstd * gamma[lane * 8 + e] + beta[lane * 8 + e]);
    #pragma unroll
    for (int e = 0; e < 4; e++)
        o4[e] = f2bf((v[8 + e] - mean) * rstd * gamma[512 + lane * 4 + e] + beta[512 + lane * 4 + e]);

    *(short8*)&src[lane * 8] = o8;
    *(short4_*)&src[512 + lane * 4] = o4;
}

extern "C" void kernel_launch(void* const* d_in, const int* in_sizes, int n_in,
                              void* d_out, int out_size, void* d_ws, size_t ws_size,
                              hipStream_t stream) {
    const float* x     = (const float*)d_in[0];   // [8192,768]
    const float* w_qkv = (const float*)d_in[1];   // [2304,768]
    const float* b_qkv = (const float*)d_in[2];
    const float* w_out = (const float*)d_in[3];   // [768,768]
    const float* b_out = (const float*)d_in[4];
    const float* gamma = (const float*)d_in[5];
    const float* beta  = (const float*)d_in[6];
    float* out = (float*)d_out;                   // [8192,768] fp32

    const int NX = 8192 * 768, NW1 = 2304 * 768, NW2 = 768 * 768;
    char* ws = (char*)d_ws;
    short* qkv   = (short*)(ws);                          // 37.75 MB
    short* xb    = (short*)(ws + (size_t)8192 * 2304 * 2);
    short* wqkvb = xb + NX;
    short* woutb = wqkvb + NW1;
    float* lbuf  = (float*)(woutb + NW2);                 // 896*128 fp32
    short* Obuf  = xb;   // recycled after gemm1 (14.68MB <= xb+wqkvb)

    // 0) one-shot fp32->bf16 conversions
    cvt3<<<dim3((NX + NW1 + NW2) / (256 * 8)), 256, 0, stream>>>(
        x, NX, w_qkv, NW1, w_out, NW2, xb, wqkvb, woutb);

    // 1) qkv = x @ w_qkv^T + b_qkv (bf16), non-dilated q cells zeroed
    gemm128<<<dim3(2304 / 128, 8192 / 128), 256, 0, stream>>>(
        xb, 768, wqkvb, b_qkv, qkv, 2304, 768);

    // 2a) split-K attention partials (overwrites xb region)
    dilated_attn_split<<<dim3(28 * 16 * 2), 256, 0, stream>>>(qkv, Obuf, lbuf);

    // 2b) merge halves, scatter into q section
    attn_combine<<<dim3(28 * 16), 256, 0, stream>>>(Obuf, lbuf, qkv);

    // 3) LayerNorm in-place on q section
    ln_inplace<<<dim3(8192 / 4), 256, 0, stream>>>(qkv, gamma, beta);

    // 4) out = LN(o) @ w_out^T + b_out (64x128 tile: 768 blocks vs 384)
    gemm64<<<dim3(768 / 128, 8192 / 64), 256, 0, stream>>>(
        qkv, 2304, woutb, b_out, out, 768, 768);
}